// Round 4
// baseline (1453.239 us; speedup 1.0000x reference)
//
#include <hip/hip_runtime.h>
#include <hip/hip_cooperative_groups.h>

namespace cg = cooperative_groups;

#define NN 16384      // nodes
#define EE 262144     // edges
#define HH 128        // hidden
#define GG 256        // graphs
#define NPG 64        // nodes per graph

// ===================== device helpers (shared by mega + fallback) =====================

// GEMM phase: C[16 rows/block x 128] = A @ W, K chunked by 32. smem: Wl[32*128] + Al[16][36]
__device__ __forceinline__ void gemm16(const float* __restrict__ A, const float* __restrict__ W,
                                       float* __restrict__ C, float* smem, int bid, int tid) {
  float* Wl = smem;                                  // [32][128]
  float (*Al)[36] = (float(*)[36])(smem + 32 * 128); // [16][36]
  int rbase = bid * 16;
  int cg = (tid & 31) * 4;
  int rg = (tid >> 5) * 2;
  float acc[2][4];
#pragma unroll
  for (int i = 0; i < 2; ++i)
#pragma unroll
    for (int j = 0; j < 4; ++j) acc[i][j] = 0.f;
  for (int kc = 0; kc < 4; ++kc) {
    int k0 = kc * 32;
    if (tid < 128) {
      int r = tid >> 3, q = tid & 7;
      float4 va = *(const float4*)&A[(rbase + r) * HH + k0 + q * 4];
      *(float4*)&Al[r][q * 4] = va;
    }
#pragma unroll
    for (int i = 0; i < 4; ++i) {
      int f = tid + 256 * i;
      int kk = f >> 5, q = f & 31;
      float4 vw = *(const float4*)&W[(k0 + kk) * HH + q * 4];
      *(float4*)&Wl[kk * 128 + q * 4] = vw;
    }
    __syncthreads();
#pragma unroll
    for (int kk = 0; kk < 32; kk += 4) {
      float av[2][4], wv_[4][4];
#pragma unroll
      for (int i = 0; i < 2; ++i) *(float4*)av[i] = *(const float4*)&Al[rg + i][kk];
#pragma unroll
      for (int j = 0; j < 4; ++j) *(float4*)wv_[j] = *(const float4*)&Wl[(kk + j) * 128 + cg];
#pragma unroll
      for (int j = 0; j < 4; ++j)
#pragma unroll
        for (int i = 0; i < 2; ++i)
#pragma unroll
          for (int c = 0; c < 4; ++c) acc[i][c] = fmaf(av[i][j], wv_[j][c], acc[i][c]);
    }
    __syncthreads();
  }
#pragma unroll
  for (int i = 0; i < 2; ++i) {
    float4 o; o.x = acc[i][0]; o.y = acc[i][1]; o.z = acc[i][2]; o.w = acc[i][3];
    *(float4*)&C[(rbase + rg + i) * HH + cg] = o;
  }
}

// Aggregate + bias + relu + residual + layernorm for nodes n = bid*4+wv, stride nwaves_total
__device__ __forceinline__ void agg_nodes(const float* __restrict__ hw, float* __restrict__ h,
    const int* __restrict__ row_ptr, const int* __restrict__ col, const float* __restrict__ dinv,
    const float* __restrict__ bias, const float* __restrict__ g, const float* __restrict__ bln,
    int bid, int tid, int nwaves_total) {
  int wv = tid >> 6, lane = tid & 63;
  int d = lane * 2;
  float2 b2 = *(const float2*)&bias[d];
  float2 gg = *(const float2*)&g[d];
  float2 bb = *(const float2*)&bln[d];
  const float2* hw2 = (const float2*)hw;
  float2* h2 = (float2*)h;
  for (int n = bid * 4 + wv; n < NN; n += nwaves_total) {
    float dn = dinv[n];
    float2 sv = hw2[n * 64 + lane];
    float a0x = sv.x * dn * dn, a0y = sv.y * dn * dn;   // self loop
    float a1x = 0.f, a1y = 0.f, a2x = 0.f, a2y = 0.f, a3x = 0.f, a3y = 0.f;
    int e0 = row_ptr[n], end = row_ptr[n + 1];
    for (int base = e0; base < end; base += 64) {
      int idx = base + lane;
      int cl = 0; float dv = 0.f;
      if (idx < end) { cl = col[idx]; dv = dinv[cl]; }
      int m = min(64, end - base);
      int j = 0;
      for (; j + 4 <= m; j += 4) {
        int s0 = __shfl(cl, j),     s1 = __shfl(cl, j + 1);
        int s2 = __shfl(cl, j + 2), s3 = __shfl(cl, j + 3);
        float n0 = __shfl(dv, j) * dn,     n1 = __shfl(dv, j + 1) * dn;
        float n2 = __shfl(dv, j + 2) * dn, n3 = __shfl(dv, j + 3) * dn;
        float2 v0 = hw2[s0 * 64 + lane];
        float2 v1 = hw2[s1 * 64 + lane];
        float2 v2 = hw2[s2 * 64 + lane];
        float2 v3 = hw2[s3 * 64 + lane];
        a0x = fmaf(v0.x, n0, a0x); a0y = fmaf(v0.y, n0, a0y);
        a1x = fmaf(v1.x, n1, a1x); a1y = fmaf(v1.y, n1, a1y);
        a2x = fmaf(v2.x, n2, a2x); a2y = fmaf(v2.y, n2, a2y);
        a3x = fmaf(v3.x, n3, a3x); a3y = fmaf(v3.y, n3, a3y);
      }
      for (; j < m; ++j) {
        int s0 = __shfl(cl, j); float n0 = __shfl(dv, j) * dn;
        float2 v0 = hw2[s0 * 64 + lane];
        a0x = fmaf(v0.x, n0, a0x); a0y = fmaf(v0.y, n0, a0y);
      }
    }
    float accx = (a0x + a1x) + (a2x + a3x);
    float accy = (a0y + a1y) + (a2y + a3y);
    float hnx = fmaxf(accx + b2.x, 0.f), hny = fmaxf(accy + b2.y, 0.f);
    float2 hv = h2[n * 64 + lane];
    float rx = hv.x + hnx, ry = hv.y + hny;
    float s1 = rx + ry, s2 = rx * rx + ry * ry;
#pragma unroll
    for (int o = 1; o < 64; o <<= 1) { s1 += __shfl_xor(s1, o); s2 += __shfl_xor(s2, o); }
    float mu = s1 * (1.f / 128.f);
    float var = s2 * (1.f / 128.f) - mu * mu;
    float rstd = rsqrtf(var + 1e-5f);
    float2 o2;
    o2.x = (rx - mu) * rstd * gg.x + bb.x;
    o2.y = (ry - mu) * rstd * gg.y + bb.y;
    h2[n * 64 + lane] = o2;
  }
}

// FA conv (deg==65) + epilogue + root readout, one graph per block, 256 threads
__device__ __forceinline__ void fa_out_graph(const float* __restrict__ hw, float* __restrict__ h,
    const float* __restrict__ bias, const float* __restrict__ g, const float* __restrict__ bln,
    const float* __restrict__ oW, const float* __restrict__ ob, float* __restrict__ out,
    float* smem, int gph, int tid) {
  float* tmp = smem;            // [256]
  float* gsum = smem + 256;     // [128]
  float (*part)[32] = (float(*)[32])(smem + 384);  // [8][32]
  int d = tid & 127, half = tid >> 7;
  const float* hwbase = hw + gph * NPG * HH;
  float s = 0.f;
#pragma unroll
  for (int r = 0; r < 32; ++r) s += hwbase[(half * 32 + r) * HH + d];
  tmp[tid] = s;
  __syncthreads();
  if (tid < 128) gsum[tid] = tmp[tid] + tmp[tid + 128];
  __syncthreads();
  int wv = tid >> 6, lane = tid & 63;
  const float inv65 = 1.0f / 65.0f;
  float2 gs = *(const float2*)&gsum[lane * 2];
  float2 b2 = *(const float2*)&bias[lane * 2];
  float2 gg = *(const float2*)&g[lane * 2];
  float2 bb = *(const float2*)&bln[lane * 2];
  __syncthreads();
  for (int ni = wv; ni < NPG; ni += 4) {
    int n = gph * NPG + ni;
    float2 hwv = ((const float2*)hw)[n * 64 + lane];
    float ax = fmaxf((gs.x + hwv.x) * inv65 + b2.x, 0.f);
    float ay = fmaxf((gs.y + hwv.y) * inv65 + b2.y, 0.f);
    float2 hv = ((float2*)h)[n * 64 + lane];
    float rx = hv.x + ax, ry = hv.y + ay;
    float s1 = rx + ry, s2 = rx * rx + ry * ry;
#pragma unroll
    for (int o = 1; o < 64; o <<= 1) { s1 += __shfl_xor(s1, o); s2 += __shfl_xor(s2, o); }
    float mu = s1 * (1.f / 128.f);
    float var = s2 * (1.f / 128.f) - mu * mu;
    float rstd = rsqrtf(var + 1e-5f);
    float2 o2;
    o2.x = (rx - mu) * rstd * gg.x + bb.x;
    o2.y = (ry - mu) * rstd * gg.y + bb.y;
    ((float2*)h)[n * 64 + lane] = o2;
    if (ni == 0) { tmp[lane * 2] = o2.x; tmp[lane * 2 + 1] = o2.y; }  // root row
  }
  __syncthreads();
  int c = tid & 31, seg = tid >> 5;
  float p = 0.f;
#pragma unroll
  for (int k = 0; k < 16; ++k) p = fmaf(tmp[seg * 16 + k], oW[(seg * 16 + k) * 32 + c], p);
  part[seg][c] = p;
  __syncthreads();
  if (tid < 32) {
    float so = ob[tid];
#pragma unroll
    for (int i = 0; i < 8; ++i) so += part[i][tid];
    out[gph * 32 + tid] = so;
  }
}

// ===================== cooperative megakernel: 1024 blocks x 256 threads =====================
__global__ __launch_bounds__(256, 4) void mega(
    const int* __restrict__ x, const int* __restrict__ ei,
    const float* __restrict__ ce, const float* __restrict__ ne,
    const float* __restrict__ Ws, const float* __restrict__ bs,
    const float* __restrict__ lg, const float* __restrict__ lb,
    const float* __restrict__ oW, const float* __restrict__ ob,
    float* __restrict__ out,
    float* __restrict__ h, float* __restrict__ hw,
    int* __restrict__ deg, float* __restrict__ dinv,
    int* __restrict__ row_ptr, int* __restrict__ cursor, int* __restrict__ col) {
  cg::grid_group grid = cg::this_grid();
  __shared__ __align__(16) float smem[32 * 128 + 16 * 36 + 32];
  int bid = blockIdx.x, tid = threadIdx.x;
  int t2 = bid * 256 + tid;                 // 0 .. 262143

  // P0: zero deg
  if (t2 < NN) deg[t2] = 0;
  grid.sync();

  // P1: embedding (2 float4 per thread) + degree atomics (1 edge per thread)
  {
#pragma unroll
    for (int u = 0; u < 2; ++u) {
      int e = t2 + u * 262144;
      int n = e >> 5, q = e & 31;
      int2 cls = ((const int2*)x)[n];
      float4 a = ((const float4*)ce)[cls.x * 32 + q];
      float4 b = ((const float4*)ne)[cls.y * 32 + q];
      float4 o; o.x = a.x + b.x; o.y = a.y + b.y; o.z = a.z + b.z; o.w = a.w + b.w;
      ((float4*)h)[e] = o;
    }
    atomicAdd(&deg[ei[EE + t2]], 1);
  }
  grid.sync();

  // P2: CSR scan (block 0 only): row_ptr, cursor, dinv
  if (bid == 0) {
    int* part = (int*)smem;
    int base = tid * 64;
    int s = 0;
    for (int i = 0; i < 64; i += 4) {
      int4 v = *(const int4*)&deg[base + i];
      s += v.x + v.y + v.z + v.w;
    }
    part[tid] = s;
    __syncthreads();
    for (int o = 1; o < 256; o <<= 1) {
      int v = part[tid];
      int add = (tid >= o) ? part[tid - o] : 0;
      __syncthreads();
      part[tid] = v + add;
      __syncthreads();
    }
    int run = tid ? part[tid - 1] : 0;
    for (int i = 0; i < 64; ++i) {
      int dv = deg[base + i];
      row_ptr[base + i] = run;
      cursor[base + i] = run;
      dinv[base + i] = rsqrtf((float)(dv + 1));
      run += dv;
    }
    if (tid == 255) row_ptr[NN] = run;   // == EE
  }
  grid.sync();

  // P3: CSR fill
  {
    int dd = ei[EE + t2];
    int p = atomicAdd(&cursor[dd], 1);
    col[p] = ei[t2];
  }
  grid.sync();

  // P4..: 3x (gemm, agg)
  for (int l = 0; l < 3; ++l) {
    gemm16(h, Ws + l * HH * HH, hw, smem, bid, tid);
    grid.sync();
    agg_nodes(hw, h, row_ptr, col, dinv, bs + l * HH, lg + l * HH, lb + l * HH, bid, tid, 4096);
    grid.sync();
  }
  gemm16(h, Ws + 3 * HH * HH, hw, smem, bid, tid);
  grid.sync();

  // P5: FA layer + readout (blocks 0..255)
  if (bid < GG) {
    fa_out_graph(hw, h, bs + 3 * HH, lg + 3 * HH, lb + 3 * HH, oW, ob, out, smem, bid, tid);
  }
}

// ===================== fallback multi-kernel path (proven R2 code) =====================
__global__ __launch_bounds__(256) void k_prep(const int* __restrict__ x,
    const float* __restrict__ ce, const float* __restrict__ ne, float* __restrict__ h,
    const int* __restrict__ ei, int* __restrict__ deg) {
  int t = blockIdx.x * 256 + threadIdx.x;
  int n = t >> 5, q = t & 31;
  int c0 = x[2 * n], c1 = x[2 * n + 1];
  float4 a = ((const float4*)ce)[c0 * 32 + q];
  float4 b = ((const float4*)ne)[c1 * 32 + q];
  float4 o; o.x = a.x + b.x; o.y = a.y + b.y; o.z = a.z + b.z; o.w = a.w + b.w;
  ((float4*)h)[t] = o;
  if (t < EE) atomicAdd(&deg[ei[EE + t]], 1);
}

__global__ __launch_bounds__(1024) void k_scan(const int* __restrict__ deg, float* __restrict__ dinv,
    int* __restrict__ row_ptr, int* __restrict__ cursor) {
  __shared__ int part[1024];
  int t = threadIdx.x;
  int base = t * 16;
  int local[16]; int s = 0;
#pragma unroll
  for (int i = 0; i < 16; ++i) { local[i] = s; s += deg[base + i]; }
  part[t] = s;
  __syncthreads();
  for (int o = 1; o < 1024; o <<= 1) {
    int v = part[t];
    int add = (t >= o) ? part[t - o] : 0;
    __syncthreads();
    part[t] = v + add;
    __syncthreads();
  }
  int pre = (t > 0) ? part[t - 1] : 0;
#pragma unroll
  for (int i = 0; i < 16; ++i) {
    int rp = pre + local[i];
    row_ptr[base + i] = rp;
    cursor[base + i] = rp;
    dinv[base + i] = rsqrtf((float)(deg[base + i] + 1));
  }
  if (t == 1023) row_ptr[NN] = part[1023];
}

__global__ __launch_bounds__(256) void k_fill(const int* __restrict__ ei,
    int* __restrict__ cursor, int* __restrict__ col) {
  int e = blockIdx.x * 256 + threadIdx.x;
  int d = ei[EE + e];
  int p = atomicAdd(&cursor[d], 1);
  col[p] = ei[e];
}

__global__ __launch_bounds__(256) void k_gemm_f(const float* __restrict__ A,
    const float* __restrict__ W, float* __restrict__ C) {
  __shared__ __align__(16) float smem[32 * 128 + 16 * 36 + 32];
  gemm16(A, W, C, smem, blockIdx.x, threadIdx.x);
}

__global__ __launch_bounds__(256) void k_agg_f(const float* __restrict__ hw, float* __restrict__ h,
    const int* __restrict__ row_ptr, const int* __restrict__ col, const float* __restrict__ dinv,
    const float* __restrict__ bias, const float* __restrict__ g, const float* __restrict__ bln) {
  agg_nodes(hw, h, row_ptr, col, dinv, bias, g, bln, blockIdx.x, threadIdx.x, NN);
}

__global__ __launch_bounds__(256) void k_fa_out_f(const float* __restrict__ hw, float* __restrict__ h,
    const float* __restrict__ bias, const float* __restrict__ g, const float* __restrict__ bln,
    const float* __restrict__ oW, const float* __restrict__ ob, float* __restrict__ out) {
  __shared__ __align__(16) float smem[1024];
  fa_out_graph(hw, h, bias, g, bln, oW, ob, out, smem, blockIdx.x, threadIdx.x);
}

extern "C" void kernel_launch(void* const* d_in, const int* in_sizes, int n_in,
                              void* d_out, int out_size, void* d_ws, size_t ws_size,
                              hipStream_t stream) {
  const int*   x  = (const int*)d_in[0];
  const int*   ei = (const int*)d_in[1];
  const float* ce = (const float*)d_in[3];
  const float* ne = (const float*)d_in[4];
  const float* Ws = (const float*)d_in[5];
  const float* bs = (const float*)d_in[6];
  const float* lg = (const float*)d_in[7];
  const float* lb = (const float*)d_in[8];
  const float* oW = (const float*)d_in[9];
  const float* ob = (const float*)d_in[10];
  float* out = (float*)d_out;

  float* h      = (float*)d_ws;
  float* hw     = h + NN * HH;
  int*   deg    = (int*)(hw + NN * HH);
  float* dinv   = (float*)(deg + NN);
  int*   row_ptr= (int*)(dinv + NN);
  int*   cursor = row_ptr + NN + 64;
  int*   col    = cursor + NN;

  void* args[18] = {(void*)&x, (void*)&ei, (void*)&ce, (void*)&ne, (void*)&Ws, (void*)&bs,
                    (void*)&lg, (void*)&lb, (void*)&oW, (void*)&ob, (void*)&out,
                    (void*)&h, (void*)&hw, (void*)&deg, (void*)&dinv,
                    (void*)&row_ptr, (void*)&cursor, (void*)&col};
  hipError_t err = hipLaunchCooperativeKernel(reinterpret_cast<void*>(mega),
                                              dim3(1024), dim3(256), args, 0u, stream);
  if (err != hipSuccess) {
    (void)hipGetLastError();   // clear sticky error; use proven multi-kernel path
    hipMemsetAsync(deg, 0, NN * sizeof(int), stream);
    k_prep<<<NN * 32 / 256, 256, 0, stream>>>(x, ce, ne, h, ei, deg);
    k_scan<<<1, 1024, 0, stream>>>(deg, dinv, row_ptr, cursor);
    k_fill<<<EE / 256, 256, 0, stream>>>(ei, cursor, col);
    for (int l = 0; l < 3; ++l) {
      k_gemm_f<<<NN / 16, 256, 0, stream>>>(h, Ws + l * HH * HH, hw);
      k_agg_f<<<NN / 4, 256, 0, stream>>>(hw, h, row_ptr, col, dinv,
                                          bs + l * HH, lg + l * HH, lb + l * HH);
    }
    k_gemm_f<<<NN / 16, 256, 0, stream>>>(h, Ws + 3 * HH * HH, hw);
    k_fa_out_f<<<GG, 256, 0, stream>>>(hw, h, bs + 3 * HH, lg + 3 * HH, lb + 3 * HH, oW, ob, out);
  }
}

// Round 6
// 204.241 us; speedup vs baseline: 7.1153x; 7.1153x over previous
//
#include <hip/hip_runtime.h>

#define NN 16384      // nodes
#define EE 262144     // edges
#define HH 128        // hidden
#define GG 256        // graphs
#define NPG 64        // nodes per graph
#define ELLW 64       // ELL width (max deg; Poisson(16) => P(>64) ~ 1e-20, guarded)

// ---------------- k_ell: ELL adjacency fill (cnt must be pre-zeroed) ----------------
__global__ __launch_bounds__(256) void k_ell(const int* __restrict__ ei,
                                             int* __restrict__ cnt, int* __restrict__ col) {
  int e = blockIdx.x * 256 + threadIdx.x;
  int d = ei[EE + e];
  int s = atomicAdd(&cnt[d], 1);
  if (s < ELLW) col[d * ELLW + s] = ei[e];   // col grouped by dst, coalesced read later
}

// ---------------- shared GEMM tail: C[rbase..rbase+31][0..127] = Al @ W ----------------
// Al: full-width 32x128 A-tile in LDS (+4 pad). Wl: 32x128 K-chunk staging. 512 threads.
__device__ __forceinline__ void gemm32(const float (*Al)[132], float* Wl,
                                       const float* __restrict__ W, float* __restrict__ C,
                                       int rbase, int tid) {
  int cg = (tid & 31) * 4;        // 4 consecutive cols
  int rg = (tid >> 5) * 2;        // 2 rows
  float acc[2][4];
#pragma unroll
  for (int i = 0; i < 2; ++i)
#pragma unroll
    for (int j = 0; j < 4; ++j) acc[i][j] = 0.f;
  for (int kc = 0; kc < 4; ++kc) {
    int k0 = kc * 32;
#pragma unroll
    for (int i = 0; i < 2; ++i) {            // stage W chunk: 1024 float4 / 512 thr
      int f = tid + 512 * i;
      int kk = f >> 5, q = f & 31;
      *(float4*)&Wl[kk * 128 + q * 4] = *(const float4*)&W[(k0 + kk) * HH + q * 4];
    }
    __syncthreads();                          // also publishes Al on first iteration
#pragma unroll
    for (int kk = 0; kk < 32; kk += 4) {
      float av[2][4], wv_[4][4];
#pragma unroll
      for (int i = 0; i < 2; ++i) *(float4*)av[i] = *(const float4*)&Al[rg + i][k0 + kk];
#pragma unroll
      for (int j = 0; j < 4; ++j) *(float4*)wv_[j] = *(const float4*)&Wl[(kk + j) * 128 + cg];
#pragma unroll
      for (int j = 0; j < 4; ++j)
#pragma unroll
        for (int i = 0; i < 2; ++i)
#pragma unroll
          for (int c = 0; c < 4; ++c) acc[i][c] = fmaf(av[i][j], wv_[j][c], acc[i][c]);
    }
    __syncthreads();
  }
#pragma unroll
  for (int i = 0; i < 2; ++i) {
    float4 o; o.x = acc[i][0]; o.y = acc[i][1]; o.z = acc[i][2]; o.w = acc[i][3];
    *(float4*)&C[(rbase + rg + i) * HH + cg] = o;
  }
}

// ---------------- k_emb_gemm: embed 32 rows -> LDS+global h, dinv, then hw = h @ W0 ----------------
__global__ __launch_bounds__(512) void k_emb_gemm(const int* __restrict__ x,
    const float* __restrict__ ce, const float* __restrict__ ne, const float* __restrict__ W,
    const int* __restrict__ cnt, float* __restrict__ h, float* __restrict__ hw,
    float* __restrict__ dinv) {
  __shared__ __align__(16) float Wl[32 * 128];
  __shared__ __align__(16) float Al[32][132];
  int tid = threadIdx.x;
  int rbase = blockIdx.x * 32;
#pragma unroll
  for (int u = 0; u < 2; ++u) {
    int idx = tid + 512 * u;                  // 0..1023 : 32 rows x 32 float4
    int r = idx >> 5, q = idx & 31;
    int2 cls = ((const int2*)x)[rbase + r];
    float4 a = ((const float4*)ce)[cls.x * 32 + q];
    float4 b = ((const float4*)ne)[cls.y * 32 + q];
    float4 o; o.x = a.x + b.x; o.y = a.y + b.y; o.z = a.z + b.z; o.w = a.w + b.w;
    *(float4*)&Al[r][q * 4] = o;
    ((float4*)h)[(rbase + r) * 32 + q] = o;
  }
  if (tid < 32) dinv[rbase + tid] = rsqrtf((float)(cnt[rbase + tid] + 1));
  gemm32(Al, Wl, W, hw, rbase, tid);          // first __syncthreads publishes Al
}

// ---------------- k_agg_gemm: finish layer l for 32 nodes (agg+bias+relu+res+LN),
//                  then hwout = h_new @ W_{l+1}. hwin/hwout MUST differ. ----------------
__global__ __launch_bounds__(512) void k_agg_gemm(const float* __restrict__ hwin,
    float* __restrict__ h, const int* __restrict__ col, const int* __restrict__ cnt,
    const float* __restrict__ dinv, const float* __restrict__ bias,
    const float* __restrict__ g, const float* __restrict__ bln,
    const float* __restrict__ W, float* __restrict__ hwout) {
  __shared__ __align__(16) float Wl[32 * 128];
  __shared__ __align__(16) float Al[32][132];
  int tid = threadIdx.x, wv = tid >> 6, lane = tid & 63;
  int rbase = blockIdx.x * 32;
  const float2* hw2 = (const float2*)hwin;
  float2* h2 = (float2*)h;
  int d = lane * 2;
  float2 b2 = *(const float2*)&bias[d];
  float2 gg = *(const float2*)&g[d];
  float2 bb = *(const float2*)&bln[d];
#pragma unroll 1
  for (int i = 0; i < 4; ++i) {
    int n = rbase + wv * 4 + i;
    float dn = dinv[n];
    float2 sv = hw2[n * 64 + lane];
    float a0x = sv.x * dn * dn, a0y = sv.y * dn * dn;   // self loop
    float a1x = 0.f, a1y = 0.f, a2x = 0.f, a2y = 0.f, a3x = 0.f, a3y = 0.f;
    int m = cnt[n]; m = m > ELLW ? ELLW : m;
    int cl = 0; float dv = 0.f;
    if (lane < m) { cl = col[n * ELLW + lane]; dv = dinv[cl]; }  // coalesced 64-wide
    int j = 0;
    for (; j + 4 <= m; j += 4) {
      int s0 = __shfl(cl, j),     s1 = __shfl(cl, j + 1);
      int s2 = __shfl(cl, j + 2), s3 = __shfl(cl, j + 3);
      float n0 = __shfl(dv, j) * dn,     n1 = __shfl(dv, j + 1) * dn;
      float n2 = __shfl(dv, j + 2) * dn, n3 = __shfl(dv, j + 3) * dn;
      float2 v0 = hw2[s0 * 64 + lane];
      float2 v1 = hw2[s1 * 64 + lane];
      float2 v2 = hw2[s2 * 64 + lane];
      float2 v3 = hw2[s3 * 64 + lane];
      a0x = fmaf(v0.x, n0, a0x); a0y = fmaf(v0.y, n0, a0y);
      a1x = fmaf(v1.x, n1, a1x); a1y = fmaf(v1.y, n1, a1y);
      a2x = fmaf(v2.x, n2, a2x); a2y = fmaf(v2.y, n2, a2y);
      a3x = fmaf(v3.x, n3, a3x); a3y = fmaf(v3.y, n3, a3y);
    }
    for (; j < m; ++j) {
      int s0 = __shfl(cl, j); float n0 = __shfl(dv, j) * dn;
      float2 v0 = hw2[s0 * 64 + lane];
      a0x = fmaf(v0.x, n0, a0x); a0y = fmaf(v0.y, n0, a0y);
    }
    float accx = (a0x + a1x) + (a2x + a3x);
    float accy = (a0y + a1y) + (a2y + a3y);
    float hnx = fmaxf(accx + b2.x, 0.f), hny = fmaxf(accy + b2.y, 0.f);
    float2 hv = h2[n * 64 + lane];
    float rx = hv.x + hnx, ry = hv.y + hny;
    float s1 = rx + ry, s2 = rx * rx + ry * ry;
#pragma unroll
    for (int o = 1; o < 64; o <<= 1) { s1 += __shfl_xor(s1, o); s2 += __shfl_xor(s2, o); }
    float mu = s1 * (1.f / 128.f);
    float var = s2 * (1.f / 128.f) - mu * mu;
    float rstd = rsqrtf(var + 1e-5f);
    float2 o2;
    o2.x = (rx - mu) * rstd * gg.x + bb.x;
    o2.y = (ry - mu) * rstd * gg.y + bb.y;
    h2[n * 64 + lane] = o2;                       // own row: safe in-place
    *(float2*)&Al[wv * 4 + i][2 * lane] = o2;     // A-tile for the fused gemm
  }
  gemm32(Al, Wl, W, hwout, rbase, tid);
}

// ---------------- k_fa_out: FA conv (deg==65) + epilogue + root readout ----------------
__global__ __launch_bounds__(256) void k_fa_out(const float* __restrict__ hw, float* __restrict__ h,
    const float* __restrict__ bias, const float* __restrict__ g, const float* __restrict__ bln,
    const float* __restrict__ oW, const float* __restrict__ ob, float* __restrict__ out) {
  __shared__ float tmp[256];
  __shared__ float gsum[128];
  __shared__ float part[8][32];
  int gph = blockIdx.x;
  int tid = threadIdx.x;
  int d = tid & 127, half = tid >> 7;
  const float* hwbase = hw + gph * NPG * HH;
  float s = 0.f;
#pragma unroll
  for (int r = 0; r < 32; ++r) s += hwbase[(half * 32 + r) * HH + d];
  tmp[tid] = s;
  __syncthreads();
  if (tid < 128) gsum[tid] = tmp[tid] + tmp[tid + 128];
  __syncthreads();
  int wv = tid >> 6, lane = tid & 63;
  const float inv65 = 1.0f / 65.0f;
  float2 gs = *(const float2*)&gsum[lane * 2];
  float2 b2 = *(const float2*)&bias[lane * 2];
  float2 gg = *(const float2*)&g[lane * 2];
  float2 bb = *(const float2*)&bln[lane * 2];
  __syncthreads();
  for (int ni = wv; ni < NPG; ni += 4) {
    int n = gph * NPG + ni;
    float2 hwv = ((const float2*)hw)[n * 64 + lane];
    float ax = fmaxf((gs.x + hwv.x) * inv65 + b2.x, 0.f);
    float ay = fmaxf((gs.y + hwv.y) * inv65 + b2.y, 0.f);
    float2 hv = ((float2*)h)[n * 64 + lane];
    float rx = hv.x + ax, ry = hv.y + ay;
    float s1 = rx + ry, s2 = rx * rx + ry * ry;
#pragma unroll
    for (int o = 1; o < 64; o <<= 1) { s1 += __shfl_xor(s1, o); s2 += __shfl_xor(s2, o); }
    float mu = s1 * (1.f / 128.f);
    float var = s2 * (1.f / 128.f) - mu * mu;
    float rstd = rsqrtf(var + 1e-5f);
    float2 o2;
    o2.x = (rx - mu) * rstd * gg.x + bb.x;
    o2.y = (ry - mu) * rstd * gg.y + bb.y;
    if (ni == 0) { tmp[lane * 2] = o2.x; tmp[lane * 2 + 1] = o2.y; }  // root row (h write skipped: unused later)
  }
  __syncthreads();
  int c = tid & 31, seg = tid >> 5;
  float p = 0.f;
#pragma unroll
  for (int k = 0; k < 16; ++k) p = fmaf(tmp[seg * 16 + k], oW[(seg * 16 + k) * 32 + c], p);
  part[seg][c] = p;
  __syncthreads();
  if (tid < 32) {
    float so = ob[tid];
#pragma unroll
    for (int i = 0; i < 8; ++i) so += part[i][tid];
    out[gph * 32 + tid] = so;
  }
}

extern "C" void kernel_launch(void* const* d_in, const int* in_sizes, int n_in,
                              void* d_out, int out_size, void* d_ws, size_t ws_size,
                              hipStream_t stream) {
  const int*   x  = (const int*)d_in[0];
  const int*   ei = (const int*)d_in[1];
  const float* ce = (const float*)d_in[3];
  const float* ne = (const float*)d_in[4];
  const float* Ws = (const float*)d_in[5];
  const float* bs = (const float*)d_in[6];
  const float* lg = (const float*)d_in[7];
  const float* lb = (const float*)d_in[8];
  const float* oW = (const float*)d_in[9];
  const float* ob = (const float*)d_in[10];
  float* out = (float*)d_out;

  float* h    = (float*)d_ws;            // [NN*HH]
  float* hwA  = h + NN * HH;             // [NN*HH]
  float* hwB  = hwA + NN * HH;           // [NN*HH]
  int*   cnt  = (int*)(hwB + NN * HH);   // [NN]
  float* dinv = (float*)(cnt + NN);      // [NN]
  int*   col  = (int*)(dinv + NN);       // [NN*ELLW]

  hipMemsetAsync(cnt, 0, NN * sizeof(int), stream);
  k_ell<<<EE / 256, 256, 0, stream>>>(ei, cnt, col);
  k_emb_gemm<<<NN / 32, 512, 0, stream>>>(x, ce, ne, Ws, cnt, h, hwA, dinv);
  k_agg_gemm<<<NN / 32, 512, 0, stream>>>(hwA, h, col, cnt, dinv,
                                          bs, lg, lb, Ws + 1 * HH * HH, hwB);
  k_agg_gemm<<<NN / 32, 512, 0, stream>>>(hwB, h, col, cnt, dinv,
                                          bs + HH, lg + HH, lb + HH, Ws + 2 * HH * HH, hwA);
  k_agg_gemm<<<NN / 32, 512, 0, stream>>>(hwA, h, col, cnt, dinv,
                                          bs + 2 * HH, lg + 2 * HH, lb + 2 * HH, Ws + 3 * HH * HH, hwB);
  k_fa_out<<<GG, 256, 0, stream>>>(hwB, h, bs + 3 * HH, lg + 3 * HH, lb + 3 * HH, oW, ob, out);
}

// Round 12
// 188.794 us; speedup vs baseline: 7.6975x; 1.0818x over previous
//
#include <hip/hip_runtime.h>

#define NN 16384      // nodes
#define EE 262144     // edges
#define HH 128        // hidden
#define GG 256        // graphs
#define NPG 64        // nodes per graph
#define ELLW 64       // ELL width (deg ~ multinomial mean 16; P(deg>64) ~ 0, guarded)

// ---------------- k_ell: ELL adjacency fill (cnt pre-zeroed) ----------------
__global__ __launch_bounds__(256) void k_ell(const int* __restrict__ ei,
                                             int* __restrict__ cnt, int* __restrict__ col) {
  int e = blockIdx.x * 256 + threadIdx.x;
  int d = ei[EE + e];
  int s = atomicAdd(&cnt[d], 1);
  if (s < ELLW) col[d * ELLW + s] = ei[e];
}

// ---------------- GEMM core: acc[2][4] = Al(32x128) @ W(128x128) tile ----------------
// 512 threads; thread owns rows rg..rg+1 (rg=(tid>>5)*2), cols cg..cg+3 (cg=(tid&31)*4).
// First __syncthreads also publishes caller-written Al.
__device__ __forceinline__ void gemm32_acc(const float (*Al)[132], float* Wl,
                                           const float* __restrict__ W, int tid,
                                           float acc[2][4]) {
  int cg = (tid & 31) * 4;
  int rg = (tid >> 5) * 2;
#pragma unroll
  for (int i = 0; i < 2; ++i)
#pragma unroll
    for (int j = 0; j < 4; ++j) acc[i][j] = 0.f;
  for (int kc = 0; kc < 4; ++kc) {
    int k0 = kc * 32;
#pragma unroll
    for (int i = 0; i < 2; ++i) {            // stage W chunk: 1024 float4 / 512 thr
      int f = tid + 512 * i;
      int kk = f >> 5, q = f & 31;
      *(float4*)&Wl[kk * 128 + q * 4] = *(const float4*)&W[(k0 + kk) * HH + q * 4];
    }
    __syncthreads();
#pragma unroll
    for (int kk = 0; kk < 32; kk += 4) {
      float av[2][4], wv_[4][4];
#pragma unroll
      for (int i = 0; i < 2; ++i) *(float4*)av[i] = *(const float4*)&Al[rg + i][k0 + kk];
#pragma unroll
      for (int j = 0; j < 4; ++j) *(float4*)wv_[j] = *(const float4*)&Wl[(kk + j) * 128 + cg];
#pragma unroll
      for (int j = 0; j < 4; ++j)
#pragma unroll
        for (int i = 0; i < 2; ++i)
#pragma unroll
          for (int c = 0; c < 4; ++c) acc[i][c] = fmaf(av[i][j], wv_[j][c], acc[i][c]);
    }
    __syncthreads();
  }
}

// ---------------- epilogue: h_out row = LN(res + relu(acc + bias)) ----------------
// 32 lanes (half-wave) hold one row (4 cols each); shfl_xor masks<=16 stay in-half.
__device__ __forceinline__ void epilogue_store(float acc[2][4], const float4 res[2],
    const float* __restrict__ bias, const float* __restrict__ g, const float* __restrict__ bln,
    float* __restrict__ h_out, int rbase, int tid) {
  int cg = (tid & 31) * 4;
  int rg = (tid >> 5) * 2;
  float4 b4 = *(const float4*)&bias[cg];
  float4 g4 = *(const float4*)&g[cg];
  float4 l4 = *(const float4*)&bln[cg];
#pragma unroll
  for (int i = 0; i < 2; ++i) {
    int n = rbase + rg + i;
    float vx = fmaxf(acc[i][0] + b4.x, 0.f) + res[i].x;
    float vy = fmaxf(acc[i][1] + b4.y, 0.f) + res[i].y;
    float vz = fmaxf(acc[i][2] + b4.z, 0.f) + res[i].z;
    float vw = fmaxf(acc[i][3] + b4.w, 0.f) + res[i].w;
    float s1 = (vx + vy) + (vz + vw);
    float s2 = (vx * vx + vy * vy) + (vz * vz + vw * vw);
#pragma unroll
    for (int o = 1; o < 32; o <<= 1) { s1 += __shfl_xor(s1, o); s2 += __shfl_xor(s2, o); }
    float mu = s1 * (1.f / 128.f);
    float var = s2 * (1.f / 128.f) - mu * mu;
    float rstd = rsqrtf(var + 1e-5f);
    float4 o4;
    o4.x = (vx - mu) * rstd * g4.x + l4.x;
    o4.y = (vy - mu) * rstd * g4.y + l4.y;
    o4.z = (vz - mu) * rstd * g4.z + l4.z;
    o4.w = (vw - mu) * rstd * g4.w + l4.w;
    *(float4*)&h_out[n * HH + cg] = o4;
  }
}

// ---------------- k_layer0: agg(emb rows) -> @W0 -> epilogue -> hA ----------------
// (gathers hit the 16KB ce/ne tables -> L1-resident; keeps float2 loop)
__global__ __launch_bounds__(512) void k_layer0(const int* __restrict__ x,
    const float* __restrict__ ce, const float* __restrict__ ne,
    const int* __restrict__ col, const int* __restrict__ cnt,
    const float* __restrict__ bias, const float* __restrict__ g, const float* __restrict__ bln,
    const float* __restrict__ W, float* __restrict__ h_out) {
  __shared__ __align__(16) float Wl[32 * 128];
  __shared__ __align__(16) float Al[32][132];
  int tid = threadIdx.x, wv = tid >> 6, lane = tid & 63;
  int rbase = blockIdx.x * 32;
  const int2* x2 = (const int2*)x;
  const float2* ce2 = (const float2*)ce;
  const float2* ne2 = (const float2*)ne;
#pragma unroll 1
  for (int i = 0; i < 4; ++i) {
    int n = rbase + wv * 4 + i;
    int cn_ = cnt[n];
    float dn = rsqrtf((float)cn_ + 1.0f);
    int2 cc = x2[n];                                   // broadcast load
    float2 e0 = ce2[cc.x * 64 + lane];
    float2 e1 = ne2[cc.y * 64 + lane];
    float svx = e0.x + e1.x, svy = e0.y + e1.y;        // emb row (self)
    float a0x = svx * dn * dn, a0y = svy * dn * dn;
    float a1x = 0.f, a1y = 0.f, a2x = 0.f, a2y = 0.f, a3x = 0.f, a3y = 0.f;
    int m = cn_ > ELLW ? ELLW : cn_;
    int pc = 0; float dv = 0.f;
    if (lane < m) {
      int cl = col[n * ELLW + lane];
      int2 cs = x2[cl];
      pc = cs.x | (cs.y << 16);
      dv = rsqrtf((float)cnt[cl] + 1.0f);
    }
    int j = 0;
    for (; j + 4 <= m; j += 4) {
      int p0 = __shfl(pc, j),     p1 = __shfl(pc, j + 1);
      int p2 = __shfl(pc, j + 2), p3 = __shfl(pc, j + 3);
      float n0 = __shfl(dv, j) * dn,     n1 = __shfl(dv, j + 1) * dn;
      float n2 = __shfl(dv, j + 2) * dn, n3 = __shfl(dv, j + 3) * dn;
      float2 r0 = ce2[(p0 & 0xffff) * 64 + lane], q0 = ne2[(p0 >> 16) * 64 + lane];
      float2 r1 = ce2[(p1 & 0xffff) * 64 + lane], q1 = ne2[(p1 >> 16) * 64 + lane];
      float2 r2 = ce2[(p2 & 0xffff) * 64 + lane], q2 = ne2[(p2 >> 16) * 64 + lane];
      float2 r3 = ce2[(p3 & 0xffff) * 64 + lane], q3 = ne2[(p3 >> 16) * 64 + lane];
      a0x = fmaf(r0.x + q0.x, n0, a0x); a0y = fmaf(r0.y + q0.y, n0, a0y);
      a1x = fmaf(r1.x + q1.x, n1, a1x); a1y = fmaf(r1.y + q1.y, n1, a1y);
      a2x = fmaf(r2.x + q2.x, n2, a2x); a2y = fmaf(r2.y + q2.y, n2, a2y);
      a3x = fmaf(r3.x + q3.x, n3, a3x); a3y = fmaf(r3.y + q3.y, n3, a3y);
    }
    for (; j < m; ++j) {
      int p0 = __shfl(pc, j); float n0 = __shfl(dv, j) * dn;
      float2 r0 = ce2[(p0 & 0xffff) * 64 + lane], q0 = ne2[(p0 >> 16) * 64 + lane];
      a0x = fmaf(r0.x + q0.x, n0, a0x); a0y = fmaf(r0.y + q0.y, n0, a0y);
    }
    Al[wv * 4 + i][2 * lane]     = (a0x + a1x) + (a2x + a3x);
    Al[wv * 4 + i][2 * lane + 1] = (a0y + a1y) + (a2y + a3y);
  }
  float acc[2][4];
  gemm32_acc(Al, Wl, W, tid, acc);
  // residual = emb rows for the epilogue's row mapping
  int cg = (tid & 31) * 4, rg = (tid >> 5) * 2;
  const float4* ce4 = (const float4*)ce;
  const float4* ne4 = (const float4*)ne;
  float4 res[2];
#pragma unroll
  for (int i = 0; i < 2; ++i) {
    int2 cc = x2[rbase + rg + i];
    float4 a = ce4[cc.x * 32 + (cg >> 2)];
    float4 b = ne4[cc.y * 32 + (cg >> 2)];
    res[i].x = a.x + b.x; res[i].y = a.y + b.y; res[i].z = a.z + b.z; res[i].w = a.w + b.w;
  }
  epilogue_store(acc, res, bias, g, bln, h_out, rbase, tid);
}

// ---------------- k_layer: agg(h_in) -> @W -> epilogue -> h_out ----------------
// Pair-wise float4 gather: lane = (half = lane>>5, c4 = lane&31); halves process
// alternating edges, one shfl_xor(32) combines. 16B/lane, half the gather instrs.
__global__ __launch_bounds__(512) void k_layer(const float* __restrict__ h_in,
    float* __restrict__ h_out, const int* __restrict__ col, const int* __restrict__ cnt,
    const float* __restrict__ bias, const float* __restrict__ g, const float* __restrict__ bln,
    const float* __restrict__ W) {
  __shared__ __align__(16) float Wl[32 * 128];
  __shared__ __align__(16) float Al[32][132];
  int tid = threadIdx.x, wv = tid >> 6, lane = tid & 63;
  int c4 = lane & 31, half = lane >> 5;
  int rbase = blockIdx.x * 32;
  const float4* h4 = (const float4*)h_in;     // row = 32 float4s
#pragma unroll 1
  for (int i = 0; i < 4; ++i) {
    int n = rbase + wv * 4 + i;
    int cn_ = cnt[n];
    float dn = rsqrtf((float)cn_ + 1.0f);
    int m = cn_ > ELLW ? ELLW : cn_;
    int cl = n; float dv = 0.f;               // pad: self with zero weight
    if (lane < m) { cl = col[n * ELLW + lane]; dv = rsqrtf((float)cnt[cl] + 1.0f); }
    float4 a0; a0.x = 0.f; a0.y = 0.f; a0.z = 0.f; a0.w = 0.f;
    float4 a1; a1.x = 0.f; a1.y = 0.f; a1.z = 0.f; a1.w = 0.f;
    int pairs = (m + 1) >> 1;                 // edge-pairs; max shfl idx = m <= 63
    int t = 0;
    for (; t + 2 <= pairs; t += 2) {          // 4 edges per iter, 2 gathers in flight/half
      int e0 = 2 * t + half, e1 = 2 * (t + 1) + half;
      int s0 = __shfl(cl, e0); float q0 = __shfl(dv, e0) * dn;
      int s1 = __shfl(cl, e1); float q1 = __shfl(dv, e1) * dn;
      float4 v0 = h4[s0 * 32 + c4];
      float4 v1 = h4[s1 * 32 + c4];
      a0.x = fmaf(v0.x, q0, a0.x); a0.y = fmaf(v0.y, q0, a0.y);
      a0.z = fmaf(v0.z, q0, a0.z); a0.w = fmaf(v0.w, q0, a0.w);
      a1.x = fmaf(v1.x, q1, a1.x); a1.y = fmaf(v1.y, q1, a1.y);
      a1.z = fmaf(v1.z, q1, a1.z); a1.w = fmaf(v1.w, q1, a1.w);
    }
    for (; t < pairs; ++t) {
      int e0 = 2 * t + half;
      int s0 = __shfl(cl, e0); float q0 = __shfl(dv, e0) * dn;
      float4 v0 = h4[s0 * 32 + c4];
      a0.x = fmaf(v0.x, q0, a0.x); a0.y = fmaf(v0.y, q0, a0.y);
      a0.z = fmaf(v0.z, q0, a0.z); a0.w = fmaf(v0.w, q0, a0.w);
    }
    float4 tt;
    tt.x = a0.x + a1.x; tt.y = a0.y + a1.y; tt.z = a0.z + a1.z; tt.w = a0.w + a1.w;
    tt.x += __shfl_xor(tt.x, 32); tt.y += __shfl_xor(tt.y, 32);
    tt.z += __shfl_xor(tt.z, 32); tt.w += __shfl_xor(tt.w, 32);
    float4 sv = h4[n * 32 + c4];              // self loop
    float w2 = dn * dn;
    tt.x = fmaf(sv.x, w2, tt.x); tt.y = fmaf(sv.y, w2, tt.y);
    tt.z = fmaf(sv.z, w2, tt.z); tt.w = fmaf(sv.w, w2, tt.w);
    if (half == 0) *(float4*)&Al[wv * 4 + i][c4 * 4] = tt;
  }
  float acc[2][4];
  gemm32_acc(Al, Wl, W, tid, acc);
  int cg = (tid & 31) * 4, rg = (tid >> 5) * 2;
  float4 res[2];
#pragma unroll
  for (int i = 0; i < 2; ++i) res[i] = *(const float4*)&h_in[(rbase + rg + i) * HH + cg];
  epilogue_store(acc, res, bias, g, bln, h_out, rbase, tid);
}

// ---------------- k_fa_root: per-graph FA layer at root only + readout ----------------
// agg_FA(h)[root] = (sum_graph h + h[root])/65; y = LN(h[root]+relu(a@W3+b3)); out = y@oW+ob
__global__ __launch_bounds__(256) void k_fa_root(const float* __restrict__ hA,
    const float* __restrict__ W3, const float* __restrict__ b3,
    const float* __restrict__ g3, const float* __restrict__ l3,
    const float* __restrict__ oW, const float* __restrict__ ob, float* __restrict__ out) {
  __shared__ float s_sum[256];
  __shared__ float s_a[128];
  __shared__ float s_hr[128];
  __shared__ float s_r[128];
  __shared__ float s_y[128];
  __shared__ float s_red[2];
  int gph = blockIdx.x, tid = threadIdx.x;
  const float* base = hA + gph * NPG * HH;
  int c = tid & 127, half = tid >> 7;
  float s = 0.f;
#pragma unroll
  for (int r = 0; r < 32; ++r) s += base[(half * 32 + r) * HH + c];
  s_sum[tid] = s;
  __syncthreads();
  if (tid < 128) {
    float gs = s_sum[tid] + s_sum[tid + 128];
    float hr = base[tid];                       // root row (node 0)
    s_hr[tid] = hr;
    s_a[tid] = (gs + hr) * (1.0f / 65.0f);
  }
  __syncthreads();
  if (tid < 128) {
    float acc = 0.f;
#pragma unroll 8
    for (int k = 0; k < 128; ++k) acc = fmaf(s_a[k], W3[k * HH + tid], acc);
    float t = fmaxf(acc + b3[tid], 0.f);
    s_r[tid] = s_hr[tid] + t;
  }
  __syncthreads();
  if (tid < 64) {
    float v0 = s_r[tid], v1 = s_r[tid + 64];
    float s1 = v0 + v1, s2 = v0 * v0 + v1 * v1;
#pragma unroll
    for (int o = 1; o < 64; o <<= 1) { s1 += __shfl_xor(s1, o); s2 += __shfl_xor(s2, o); }
    if (tid == 0) {
      float mu = s1 * (1.f / 128.f);
      float var = s2 * (1.f / 128.f) - mu * mu;
      s_red[0] = mu; s_red[1] = rsqrtf(var + 1e-5f);
    }
  }
  __syncthreads();
  if (tid < 128) {
    float mu = s_red[0], rstd = s_red[1];
    s_y[tid] = (s_r[tid] - mu) * rstd * g3[tid] + l3[tid];
  }
  __syncthreads();
  if (tid < 32) {
    float acc = ob[tid];
#pragma unroll 8
    for (int k = 0; k < 128; ++k) acc = fmaf(s_y[k], oW[k * 32 + tid], acc);
    out[gph * 32 + tid] = acc;
  }
}

extern "C" void kernel_launch(void* const* d_in, const int* in_sizes, int n_in,
                              void* d_out, int out_size, void* d_ws, size_t ws_size,
                              hipStream_t stream) {
  const int*   x  = (const int*)d_in[0];
  const int*   ei = (const int*)d_in[1];
  const float* ce = (const float*)d_in[3];
  const float* ne = (const float*)d_in[4];
  const float* Ws = (const float*)d_in[5];
  const float* bs = (const float*)d_in[6];
  const float* lg = (const float*)d_in[7];
  const float* lb = (const float*)d_in[8];
  const float* oW = (const float*)d_in[9];
  const float* ob = (const float*)d_in[10];
  float* out = (float*)d_out;

  float* hA  = (float*)d_ws;             // [NN*HH]
  float* hB  = hA + NN * HH;             // [NN*HH]
  int*   cnt = (int*)(hB + NN * HH);     // [NN]
  int*   col = cnt + NN;                 // [NN*ELLW]

  hipMemsetAsync(cnt, 0, NN * sizeof(int), stream);
  k_ell<<<EE / 256, 256, 0, stream>>>(ei, cnt, col);
  k_layer0<<<NN / 32, 512, 0, stream>>>(x, ce, ne, col, cnt,
                                        bs, lg, lb, Ws, hA);
  k_layer<<<NN / 32, 512, 0, stream>>>(hA, hB, col, cnt,
                                       bs + HH, lg + HH, lb + HH, Ws + HH * HH);
  k_layer<<<NN / 32, 512, 0, stream>>>(hB, hA, col, cnt,
                                       bs + 2 * HH, lg + 2 * HH, lb + 2 * HH, Ws + 2 * HH * HH);
  k_fa_root<<<GG, 256, 0, stream>>>(hA, Ws + 3 * HH * HH, bs + 3 * HH,
                                    lg + 3 * HH, lb + 3 * HH, oW, ob, out);
}